// Round 19
// baseline (113.152 us; speedup 1.0000x reference)
//
#include <hip/hip_runtime.h>
#include <hip/hip_bf16.h>
#include <math.h>

#define T_NODES 8192
#define BGRAPHS 16
#define CDIM 128
#define HEADS 4
#define DHEAD 32
#define KNN 16

// ---------------------------------------------------------------------------
// Wave-parallel segment probe (verified R13): stride-16 coarse + 16-wide fine.
// ---------------------------------------------------------------------------
__device__ __forceinline__ void seg_probe(const int* __restrict__ batch, int t,
                                          int lane, int& s_out, int& n_out) {
    int b = batch[t];
    int pb = t - lane * 16;
    int qf = t + lane * 16;
    int vb = batch[pb < 0 ? 0 : pb];
    int vf = batch[qf > T_NODES - 1 ? T_NODES - 1 : qf];
    bool eqb = (pb >= 0) && (vb == b);
    bool eqf = (qf < T_NODES) && (vf == b);
    unsigned long long mb = __ballot(eqb);
    unsigned long long mf = __ballot(eqf);
    int m1 = (~mb == 0ULL) ? 64 : (int)__builtin_ctzll(~mb);
    int m2 = (~mf == 0ULL) ? 64 : (int)__builtin_ctzll(~mf);
    int wsb = (m1 == 64) ? (t - 1023) : (t - m1 * 16 + 1);
    int wsf = (m2 == 64) ? (t + 1009) : (t + (m2 - 1) * 16 + 1);
    int pos2 = (lane < 16) ? (wsb + lane) : (wsf + (lane - 16));
    int pc = pos2 < 0 ? 0 : (pos2 > T_NODES - 1 ? T_NODES - 1 : pos2);
    int v2 = batch[pc];
    bool cb = (lane < 16) && ((pos2 < 0) || (v2 < b));
    bool cf = (lane >= 16) && (lane < 32) && (pos2 < T_NODES) && (v2 == b);
    s_out = wsb + (int)__popcll(__ballot(cb));
    n_out = wsf + (int)__popcll(__ballot(cf)) - s_out;
}

// ---------------------------------------------------------------------------
// Full-wave kNN body (verified R13): fallback path, NS slots/lane, 64 lanes.
// ---------------------------------------------------------------------------
template <int NS>
__device__ __forceinline__ void knn_body(const float* __restrict__ pos,
                                         int t, int s, int n, int lane,
                                         int* __restrict__ nbr,
                                         float4* __restrict__ dird) {
    float px = pos[t * 3 + 0], py = pos[t * 3 + 1], pz = pos[t * 3 + 2];
    float sd[NS];
    int ss[NS];
#pragma unroll
    for (int sl = 0; sl < NS; ++sl) {
        int j = lane + sl * 64;
        float d2 = 1e30f;
        if (j < n) {
            int jj = s + j;
            float dx = px - pos[jj * 3 + 0];
            float dy = py - pos[jj * 3 + 1];
            float dz = pz - pos[jj * 3 + 2];
            d2 = dx * dx + dy * dy + dz * dz;
        }
        sd[sl] = d2;
        ss[sl] = sl;
    }
#pragma unroll
    for (int p = 1; p < NS; p <<= 1) {
#pragma unroll
        for (int k = p; k >= 1; k >>= 1) {
#pragma unroll
            for (int j = (k & (p - 1)); j + k < NS; j += 2 * k) {
#pragma unroll
                for (int i = 0; i < k; ++i) {
                    if (i + j + k < NS && ((i + j) / (2 * p)) == ((i + j + k) / (2 * p))) {
                        int a = i + j, c2 = i + j + k;
                        bool sw = sd[a] > sd[c2];
                        float td = sd[a];
                        int ts = ss[a];
                        sd[a] = sw ? sd[c2] : sd[a];
                        ss[a] = sw ? ss[c2] : ss[a];
                        sd[c2] = sw ? td : sd[c2];
                        ss[c2] = sw ? ts : ss[c2];
                    }
                }
            }
        }
    }

    float resd = 1e30f;
    int resj = -1;
#pragma unroll
    for (int r = 0; r < KNN; ++r) {
        float rd = sd[0];
#pragma unroll
        for (int off = 32; off >= 1; off >>= 1) {
            rd = fminf(rd, __shfl_xor(rd, off));
        }
        unsigned long long mask = __ballot(sd[0] == rd);
        int wl = (int)__builtin_ctzll(mask);
        int ws = __shfl(ss[0], wl);
        if (lane == r) { resd = rd; resj = wl + ws * 64; }
        if (lane == wl) {
#pragma unroll
            for (int i = 0; i < NS - 1; ++i) { sd[i] = sd[i + 1]; ss[i] = ss[i + 1]; }
            sd[NS - 1] = 1e30f;
        }
    }

    if (lane < KNN) {
        bool valid = (resd < 1e29f);
        int jf = valid ? (s + resj) : -1;
        nbr[t * KNN + lane] = jf;
        float dd = sqrtf(resd + 1e-6f);
        float dx = 0.f, dy = 0.f, dz = 0.f;
        if (valid) {
            float inv = 1.f / dd;
            dx = (px - pos[jf * 3 + 0]) * inv;
            dy = (py - pos[jf * 3 + 1]) * inv;
            dz = (pz - pos[jf * 3 + 2]) * inv;
        }
        float4 v;
        v.x = dx; v.y = dy; v.z = dz; v.w = dd;
        dird[t * KNN + lane] = v;
    }
}

// ---------------------------------------------------------------------------
// tau-threshold paired kNN, capacity 64 (R19): 2 nodes/wave, 18 slots/lane.
// tau = 16th-smallest of 32 lane-mins (upper bound on global 16th). Collect
// all M <= 64 candidates to LDS; sort both 32-blocks in one register-paired
// bitonic; bitonic-merge (reverse + min + 5-stage clean) -> exact top-16.
// Fallback only if M > 64 (astronomically rare for continuous coords).
// ---------------------------------------------------------------------------
__device__ __forceinline__ bool knn_tau(const float* __restrict__ pos,
                                        int t, int s, int n, int lane,
                                        float* __restrict__ ldsD,
                                        int* __restrict__ ldsI,
                                        int* __restrict__ nbr,
                                        float4* __restrict__ dird) {
    const int NS = 18;
    int l32 = lane & 31;
    float px = pos[t * 3 + 0], py = pos[t * 3 + 1], pz = pos[t * 3 + 2];
    float sd[NS];
#pragma unroll
    for (int sl = 0; sl < NS; ++sl) {
        int j = l32 + sl * 32;
        float d2 = 1e30f;
        if (j < n) {
            int jj = s + j;
            float dx = px - pos[jj * 3 + 0];
            float dy = py - pos[jj * 3 + 1];
            float dz = pz - pos[jj * 3 + 2];
            d2 = dx * dx + dy * dy + dz * dz;
        }
        sd[sl] = d2;
    }
    float v = sd[0];
#pragma unroll
    for (int sl = 1; sl < NS; ++sl) v = fminf(v, sd[sl]);
#pragma unroll
    for (int k = 2; k <= 32; k <<= 1) {
#pragma unroll
        for (int j = k >> 1; j > 0; j >>= 1) {
            float o = __shfl_xor(v, j);
            bool up = ((l32 & k) == 0);
            bool lower = ((l32 & j) == 0);
            v = (lower == up) ? fminf(v, o) : fmaxf(v, o);
        }
    }
    float tau = __shfl(v, (lane & 32) + 15);

    int cnt = 0;
#pragma unroll
    for (int sl = 0; sl < NS; ++sl) cnt += (sd[sl] <= tau) ? 1 : 0;
    int pfx = cnt;
#pragma unroll
    for (int off = 1; off < 32; off <<= 1) {
        int y = __shfl(pfx, lane - off);
        if (l32 >= off) pfx += y;
    }
    int M = __shfl(pfx, (lane & 32) + 31);
    if (__ballot(M > 64)) return false;  // ~never

    int wp = pfx - cnt;
    float* bd = ldsD + (lane >> 5) * 64;
    int* bi = ldsI + (lane >> 5) * 64;
#pragma unroll
    for (int sl = 0; sl < NS; ++sl) {
        if (sd[sl] <= tau) { bd[wp] = sd[sl]; bi[wp] = l32 + sl * 32; ++wp; }
    }
    __asm__ volatile("s_waitcnt lgkmcnt(0)" ::: "memory");

    // load two 32-blocks of candidates (pad with +inf)
    float kd0 = (l32 < M) ? bd[l32] : 1e30f;
    int ki0 = (l32 < M) ? bi[l32] : 0;
    float kd1 = (l32 + 32 < M) ? bd[l32 + 32] : 1e30f;
    int ki1 = (l32 + 32 < M) ? bi[l32 + 32] : 0;

    // sort both blocks ascending (register-paired bitonic, shared stages)
#pragma unroll
    for (int k = 2; k <= 32; k <<= 1) {
#pragma unroll
        for (int j = k >> 1; j > 0; j >>= 1) {
            float od0 = __shfl_xor(kd0, j);
            int oi0 = __shfl_xor(ki0, j);
            float od1 = __shfl_xor(kd1, j);
            int oi1 = __shfl_xor(ki1, j);
            bool up = ((l32 & k) == 0);
            bool lower = ((l32 & j) == 0);
            bool keepMin = (lower == up);
            bool take0 = keepMin ? (od0 < kd0) : (od0 > kd0);
            kd0 = keepMin ? fminf(kd0, od0) : fmaxf(kd0, od0);
            ki0 = take0 ? oi0 : ki0;
            bool take1 = keepMin ? (od1 < kd1) : (od1 > kd1);
            kd1 = keepMin ? fminf(kd1, od1) : fmaxf(kd1, od1);
            ki1 = take1 ? oi1 : ki1;
        }
    }

    // merge: reverse block 1 (half-local), elementwise min -> bitonic lo-seq
    {
        int src = (lane & 32) + (31 - l32);
        float rd1 = __shfl(kd1, src);
        int ri1 = __shfl(ki1, src);
        bool take = rd1 < kd0;
        kd0 = take ? rd1 : kd0;
        ki0 = take ? ri1 : ki0;
    }
    // clean bitonic sequence ascending (5 stages)
#pragma unroll
    for (int j = 16; j >= 1; j >>= 1) {
        float od = __shfl_xor(kd0, j);
        int oi = __shfl_xor(ki0, j);
        bool lower = ((l32 & j) == 0);
        bool take = lower ? (od < kd0) : (od > kd0);
        kd0 = lower ? fminf(kd0, od) : fmaxf(kd0, od);
        ki0 = take ? oi : ki0;
    }

    if (l32 < KNN) {
        bool valid = (kd0 < 1e29f);
        int jf = valid ? (s + ki0) : -1;
        nbr[t * KNN + l32] = jf;
        float dd = sqrtf(kd0 + 1e-6f);
        float dx = 0.f, dy = 0.f, dz = 0.f;
        if (valid) {
            float inv = 1.f / dd;
            dx = (px - pos[jf * 3 + 0]) * inv;
            dy = (py - pos[jf * 3 + 1]) * inv;
            dz = (pz - pos[jf * 3 + 2]) * inv;
        }
        float4 vv;
        vv.x = dx; vv.y = dy; vv.z = dz; vv.w = dd;
        dird[t * KNN + l32] = vv;
    }
    return true;
}

// ---------------------------------------------------------------------------
// Kernel 1: k_par — ONE dispatch, three concurrent roles (mod-3 partition,
// R15 config: A=1024x8-node kNN, B=512x16-node QKV, C=2 head-folds).
// Role A: shared seg_probe for same-segment node pairs (R18) + capacity-64
// tau path (R19, ~eliminates fallback stragglers).
// ---------------------------------------------------------------------------
__global__ __launch_bounds__(256) void k_par(const float* __restrict__ pos,
                                             const int* __restrict__ batch,
                                             const float* __restrict__ x,
                                             const float* __restrict__ embW,
                                             const float* __restrict__ embb,
                                             const float* __restrict__ Wq,
                                             const float* __restrict__ Wk,
                                             const float* __restrict__ Wv0,
                                             const float* __restrict__ Wv1,
                                             const float* __restrict__ Wo0,
                                             const float* __restrict__ Wg,
                                             const float* __restrict__ headW,
                                             int* __restrict__ nbr,
                                             float4* __restrict__ dird,
                                             float* __restrict__ qkvv,
                                             float* __restrict__ poolF0,
                                             float* __restrict__ H1,
                                             float* __restrict__ H2) {
    __shared__ float smem[CDIM * 20];  // 10 KB: qkv tile / headW / knn bufD
    __shared__ int smemi[512];         // role A bufI (4 waves x 128)
    int bid = blockIdx.x;
    int tid = threadIdx.x;

    if (bid >= 1536) {
        // ---- role C: H1/H2 = {Wo0,Wg} @ headW ----
        int m = bid - 1536;
        const float* W = m ? Wg : Wo0;
        float* H = m ? H2 : H1;
        for (int i = tid; i < CDIM * 19; i += 256) smem[i] = headW[i];
        __syncthreads();
        for (int i = tid; i < CDIM * 19; i += 256) {
            int c = i / 19, o = i - c * 19;
            float acc = 0.f;
#pragma unroll 8
            for (int d = 0; d < CDIM; ++d) acc += W[c * CDIM + d] * smem[d * 19 + o];
            H[i] = acc;
        }
        return;
    }

    int g = bid / 3, r = bid - g * 3;
    if (r == 2) {
        // ---- role B: embed + QKV for nodes [g*16, g*16+16), f0 pooled ----
        float (*sf)[CDIM] = (float (*)[CDIM])smem;
        int t0 = g * 16;
        {
            int col = tid & 127;
            int pr = tid >> 7;
            float ew[11];
#pragma unroll
            for (int i = 0; i < 11; ++i) ew[i] = embW[i * CDIM + col];
            float eb = embb[col];
            float acc_run = 0.f;
            int gprev = batch[t0 + pr * 8];
#pragma unroll
            for (int nn8 = 0; nn8 < 8; ++nn8) {
                int nn = pr * 8 + nn8;
                int t = t0 + nn;
                float acc = eb;
#pragma unroll
                for (int i = 0; i < 11; ++i) acc += x[t * 11 + i] * ew[i];
                sf[nn][col] = acc;
                int gb = batch[t];
                if (gb != gprev) {
                    atomicAdd(&poolF0[gprev * CDIM + col], acc_run);
                    acc_run = 0.f;
                    gprev = gb;
                }
                acc_run += acc;
            }
            atomicAdd(&poolF0[gprev * CDIM + col], acc_run);
        }
        __syncthreads();

        const float* W1 = (tid < 128) ? Wq : Wk;    // wave-uniform
        const float* W2 = (tid < 128) ? Wv0 : Wv1;  // wave-uniform
        int col = tid & 127;

        float acc1[16], acc2[16];
#pragma unroll
        for (int nn = 0; nn < 16; ++nn) { acc1[nn] = 0.f; acc2[nn] = 0.f; }

        for (int c0 = 0; c0 < CDIM; c0 += 8) {
            float w1[8], w2[8];
#pragma unroll
            for (int cc = 0; cc < 8; ++cc) {
                w1[cc] = W1[(c0 + cc) * CDIM + col];
                w2[cc] = W2[(c0 + cc) * CDIM + col];
            }
#pragma unroll
            for (int nn = 0; nn < 16; ++nn) {
                float4 fa = *(const float4*)&sf[nn][c0];
                float4 fb = *(const float4*)&sf[nn][c0 + 4];
                acc1[nn] += fa.x * w1[0] + fa.y * w1[1] + fa.z * w1[2] + fa.w * w1[3]
                          + fb.x * w1[4] + fb.y * w1[5] + fb.z * w1[6] + fb.w * w1[7];
                acc2[nn] += fa.x * w2[0] + fa.y * w2[1] + fa.z * w2[2] + fa.w * w2[3]
                          + fb.x * w2[4] + fb.y * w2[5] + fb.z * w2[6] + fb.w * w2[7];
            }
        }
#pragma unroll
        for (int nn = 0; nn < 16; ++nn) {
            qkvv[(size_t)(t0 + nn) * 512 + tid] = acc1[nn];
            qkvv[(size_t)(t0 + nn) * 512 + 256 + tid] = acc2[nn];
        }
        return;
    }

    // ---- role A: kNN, 2 nodes per wave (8 per block) ----
    int kidx = g * 2 + r;           // 0..1023
    int wave = tid >> 6;
    int lane = tid & 63;
    int tA = kidx * 8 + wave * 2;
    int tB = tA + 1;

    int sA, nA, sB, nB;
    seg_probe(batch, tA, lane, sA, nA);
    if (batch[tB] == batch[tA]) {   // wave-uniform; ~511/512 of waves
        sB = sA; nB = nA;
    } else {
        seg_probe(batch, tB, lane, sB, nB);
    }

    float* ldsD = smem + wave * 128;
    int* ldsI = smemi + wave * 128;

    int nmax = nA > nB ? nA : nB;
    bool done = false;
    if (nmax <= 576) {
        int t = (lane < 32) ? tA : tB;
        int s = (lane < 32) ? sA : sB;
        int n = (lane < 32) ? nA : nB;
        done = knn_tau(pos, t, s, n, lane, ldsD, ldsI, nbr, dird);
    }
    if (!done) {
        knn_body<16>(pos, tA, sA, nA, lane, nbr, dird);
        knn_body<16>(pos, tB, sB, nB, lane, nbr, dird);
    }
}

// ---------------------------------------------------------------------------
// Kernel 2: fused kNN attention + equivariant mix + per-graph pooling.
// (identical to R14/R15/R18 — verified)
// ---------------------------------------------------------------------------
__global__ __launch_bounds__(256) void k_attn(const float* __restrict__ qkvv,
                                              const int* __restrict__ nbr,
                                              const float4* __restrict__ dird,
                                              const int* __restrict__ batch,
                                              const float* __restrict__ dist_scale,
                                              const float* __restrict__ Wo1,
                                              float* __restrict__ poolO0,
                                              float* __restrict__ poolInv) {
    __shared__ float  s_a[4][64];          // [node][h*16+k]
    __shared__ float4 s_d[4][16];          // dird per node
    __shared__ int    s_j[4][16];          // neighbor ids
    __shared__ float  s_o1[4][CDIM][4];    // [node][c][x,y,z,out0] = 8 KB
    __shared__ float  s_part[CDIM][13];    // half-1 partials, padded stride
    __shared__ int    s_gid[4];            // graph ids of the 4 nodes

    int bid = blockIdx.x;
    int swz = (bid & 7) * (T_NODES / 32) + (bid >> 3);  // XCD swizzle (bijective)
    int wave = threadIdx.x >> 6;
    int lane = threadIdx.x & 63;
    int t0 = swz * 4;
    int t = t0 + wave;

    if (threadIdx.x < 4) s_gid[threadIdx.x] = batch[t0 + threadIdx.x];

    // ---- Phase A: logits + softmax. lane = (k, h) ----
    int k = lane & 15;
    int h = lane >> 4;

    int j = nbr[t * KNN + k];
    float4 dv = dird[t * KNN + k];
    if (h == 0) { s_j[wave][k] = j; s_d[wave][k] = dv; }

    const float4* qv = (const float4*)&qkvv[(size_t)t * 512 + h * DHEAD];
    const float4* kv = (j >= 0) ? (const float4*)&qkvv[(size_t)j * 512 + 128 + h * DHEAD] : qv;
    float dot = 0.f;
#pragma unroll
    for (int i = 0; i < 8; ++i) {
        float4 a = qv[i], b2 = kv[i];
        dot += a.x * b2.x + a.y * b2.y + a.z * b2.z + a.w * b2.w;
    }
    float xs = dist_scale[h];
    float sp = (xs > 20.f) ? xs : log1pf(expf(xs));  // softplus
    float lg = (j >= 0) ? (dot * 0.17677669529663687f - sp * dv.w) : -1e30f;

    float m = lg;
    m = fmaxf(m, __shfl_xor(m, 1));
    m = fmaxf(m, __shfl_xor(m, 2));
    m = fmaxf(m, __shfl_xor(m, 4));
    m = fmaxf(m, __shfl_xor(m, 8));
    float e = expf(lg - m);
    float ssum = e;
    ssum += __shfl_xor(ssum, 1);
    ssum += __shfl_xor(ssum, 2);
    ssum += __shfl_xor(ssum, 4);
    ssum += __shfl_xor(ssum, 8);
    s_a[wave][h * 16 + k] = e / ssum;

    __syncthreads();

    // ---- Phase B: PV accumulate. lane handles channels 2*lane, 2*lane+1 ----
    int c2 = lane * 2;
    int hh = lane >> 4;

    float o0x = 0.f, o0y = 0.f;
    float o1xx = 0.f, o1xy = 0.f;
    float o1yx = 0.f, o1yy = 0.f;
    float o1zx = 0.f, o1zy = 0.f;

#pragma unroll
    for (int kk = 0; kk < KNN; ++kk) {
        int jj = s_j[wave][kk];
        if (jj >= 0) {
            float a = s_a[wave][hh * 16 + kk];
            float4 d = s_d[wave][kk];
            float2 v0 = *(const float2*)&qkvv[(size_t)jj * 512 + 256 + c2];
            float2 v1 = *(const float2*)&qkvv[(size_t)jj * 512 + 384 + c2];
            o0x += a * v0.x;
            o0y += a * v0.y;
            float w1x = a * v1.x, w1y = a * v1.y;
            o1xx += w1x * d.x; o1xy += w1y * d.x;
            o1yx += w1x * d.y; o1yy += w1y * d.y;
            o1zx += w1x * d.z; o1zy += w1y * d.z;
        }
    }

    {
        float4 w0; w0.x = o1xx; w0.y = o1yx; w0.z = o1zx; w0.w = o0x;
        float4 w1; w1.x = o1xy; w1.y = o1yy; w1.z = o1zy; w1.w = o0y;
        *(float4*)&s_o1[wave][c2][0] = w0;
        *(float4*)&s_o1[wave][c2 + 1][0] = w1;
    }
    __syncthreads();

    // ---- Phase C: block-cooperative f1 = out1 @ Wo1, pooled atomics ----
    int d = threadIdx.x & 127;
    int half = threadIdx.x >> 7;

    float acc[4][3];
#pragma unroll
    for (int nn = 0; nn < 4; ++nn) { acc[nn][0] = 0.f; acc[nn][1] = 0.f; acc[nn][2] = 0.f; }

    int cb0 = half * 64;
#pragma unroll 4
    for (int c = cb0; c < cb0 + 64; ++c) {
        float wv = Wo1[c * CDIM + d];  // coalesced row read, L2-hot
#pragma unroll
        for (int nn = 0; nn < 4; ++nn) {
            float4 v = *(const float4*)&s_o1[nn][c][0];  // broadcast
            acc[nn][0] += v.x * wv;
            acc[nn][1] += v.y * wv;
            acc[nn][2] += v.z * wv;
        }
    }
    if (half == 1) {
#pragma unroll
        for (int nn = 0; nn < 4; ++nn) {
            s_part[d][nn * 3 + 0] = acc[nn][0];
            s_part[d][nn * 3 + 1] = acc[nn][1];
            s_part[d][nn * 3 + 2] = acc[nn][2];
        }
    }
    __syncthreads();
    if (half == 0) {
        float accO = 0.f, accI = 0.f;
        int gprev = s_gid[0];
#pragma unroll
        for (int nn = 0; nn < 4; ++nn) {
            float fx = acc[nn][0] + s_part[d][nn * 3 + 0];
            float fy = acc[nn][1] + s_part[d][nn * 3 + 1];
            float fz = acc[nn][2] + s_part[d][nn * 3 + 2];
            float iv = sqrtf(fx * fx + fy * fy + fz * fz + 1e-6f);
            float o0v = s_o1[nn][d][3];
            int gb = s_gid[nn];
            if (gb != gprev) {
                atomicAdd(&poolO0[gprev * CDIM + d], accO);
                atomicAdd(&poolInv[gprev * CDIM + d], accI);
                accO = 0.f; accI = 0.f;
                gprev = gb;
            }
            accO += o0v;
            accI += iv;
        }
        atomicAdd(&poolO0[gprev * CDIM + d], accO);
        atomicAdd(&poolInv[gprev * CDIM + d], accI);
    }
}

// ---------------------------------------------------------------------------
// Kernel 3: tiny head — normalize pooled sums, apply headW/H1/H2 + bias.
// ---------------------------------------------------------------------------
__global__ __launch_bounds__(640) void k_pool(const float* __restrict__ poolF0,
                                              const float* __restrict__ poolO0,
                                              const float* __restrict__ poolInv,
                                              const int* __restrict__ batch,
                                              const float* __restrict__ headW,
                                              const float* __restrict__ H1,
                                              const float* __restrict__ H2,
                                              const float* __restrict__ headb,
                                              float* __restrict__ out) {
    __shared__ float P0[CDIM], P1[CDIM], P2[CDIM];
    int b = blockIdx.x;
    int tid = threadIdx.x;

    int lo = 0, hi = T_NODES;
    while (lo < hi) {
        int mid = (lo + hi) >> 1;
        bool lt = batch[mid] < b;
        lo = lt ? mid + 1 : lo;
        hi = lt ? hi : mid;
    }
    int s = lo;
    lo = 0; hi = T_NODES;
    while (lo < hi) {
        int mid = (lo + hi) >> 1;
        bool le = batch[mid] <= b;
        lo = le ? mid + 1 : lo;
        hi = le ? hi : mid;
    }
    int n = lo - s;
    float inv_n = 1.f / fmaxf((float)n, 1.f);

    if (tid < CDIM) {
        P0[tid] = poolF0[b * CDIM + tid] * inv_n;
        P1[tid] = poolO0[b * CDIM + tid] * inv_n;
        P2[tid] = poolInv[b * CDIM + tid] * inv_n;
    }
    __syncthreads();

    if (tid < 19 * 32) {
        int o = tid >> 5;
        int l = tid & 31;
        float p = 0.f;
#pragma unroll
        for (int cc = 0; cc < 4; ++cc) {
            int ch = l + cc * 32;
            p += P0[ch] * headW[ch * 19 + o]
               + P1[ch] * H1[ch * 19 + o]
               + P2[ch] * H2[ch * 19 + o];
        }
        p += __shfl_xor(p, 16);
        p += __shfl_xor(p, 8);
        p += __shfl_xor(p, 4);
        p += __shfl_xor(p, 2);
        p += __shfl_xor(p, 1);
        if (l == 0) out[b * 19 + o] = p + headb[o];
    }
}

// ---------------------------------------------------------------------------
extern "C" void kernel_launch(void* const* d_in, const int* in_sizes, int n_in,
                              void* d_out, int out_size, void* d_ws, size_t ws_size,
                              hipStream_t stream) {
    const float* x    = (const float*)d_in[0];   // [T,11]
    const float* pos  = (const float*)d_in[1];   // [T,3]
    const int* batch  = (const int*)d_in[2];     // [T]
    const float* embW = (const float*)d_in[3];   // [11,128]
    const float* embb = (const float*)d_in[4];   // [128]
    const float* Wq   = (const float*)d_in[5];
    const float* Wk   = (const float*)d_in[6];
    const float* Wv0  = (const float*)d_in[7];
    const float* Wv1  = (const float*)d_in[8];
    const float* Wo0  = (const float*)d_in[9];
    const float* Wo1  = (const float*)d_in[10];
    const float* Wg   = (const float*)d_in[11];
    const float* dist_scale = (const float*)d_in[12];  // [4]
    const float* headW = (const float*)d_in[13];       // [128,19]
    const float* headb = (const float*)d_in[14];       // [19]
    float* out = (float*)d_out;                        // [16,19]

    char* w = (char*)d_ws;
    float* qkvv = (float*)(w + 256);
    int* nbr    = (int*)(qkvv + (size_t)T_NODES * 512);
    float4* dird = (float4*)(nbr + (size_t)T_NODES * KNN);  // [T][K] {dx,dy,dz,dist}
    float* poolF0 = (float*)(dird + (size_t)T_NODES * KNN); // [16][128] x3 contiguous
    float* poolO0 = poolF0 + BGRAPHS * CDIM;
    float* poolInv = poolO0 + BGRAPHS * CDIM;
    float* H1   = poolInv + BGRAPHS * CDIM;
    float* H2   = H1 + CDIM * 19;

    hipMemsetAsync(poolF0, 0, 3 * BGRAPHS * CDIM * sizeof(float), stream);
    k_par<<<1538, 256, 0, stream>>>(pos, batch, x, embW, embb, Wq, Wk, Wv0, Wv1,
                                    Wo0, Wg, headW, nbr, dird, qkvv, poolF0, H1, H2);
    k_attn<<<T_NODES / 4, 256, 0, stream>>>(qkvv, nbr, dird, batch, dist_scale, Wo1,
                                            poolO0, poolInv);
    k_pool<<<BGRAPHS, 640, 0, stream>>>(poolF0, poolO0, poolInv, batch, headW,
                                        H1, H2, headb, out);
}

// Round 20
// 110.750 us; speedup vs baseline: 1.0217x; 1.0217x over previous
//
#include <hip/hip_runtime.h>
#include <hip/hip_bf16.h>
#include <math.h>

#define T_NODES 8192
#define BGRAPHS 16
#define CDIM 128
#define HEADS 4
#define DHEAD 32
#define KNN 16

// ---------------------------------------------------------------------------
// Wave-parallel segment probe (verified R13): stride-16 coarse + 16-wide fine.
// ---------------------------------------------------------------------------
__device__ __forceinline__ void seg_probe(const int* __restrict__ batch, int t,
                                          int lane, int& s_out, int& n_out) {
    int b = batch[t];
    int pb = t - lane * 16;
    int qf = t + lane * 16;
    int vb = batch[pb < 0 ? 0 : pb];
    int vf = batch[qf > T_NODES - 1 ? T_NODES - 1 : qf];
    bool eqb = (pb >= 0) && (vb == b);
    bool eqf = (qf < T_NODES) && (vf == b);
    unsigned long long mb = __ballot(eqb);
    unsigned long long mf = __ballot(eqf);
    int m1 = (~mb == 0ULL) ? 64 : (int)__builtin_ctzll(~mb);
    int m2 = (~mf == 0ULL) ? 64 : (int)__builtin_ctzll(~mf);
    int wsb = (m1 == 64) ? (t - 1023) : (t - m1 * 16 + 1);
    int wsf = (m2 == 64) ? (t + 1009) : (t + (m2 - 1) * 16 + 1);
    int pos2 = (lane < 16) ? (wsb + lane) : (wsf + (lane - 16));
    int pc = pos2 < 0 ? 0 : (pos2 > T_NODES - 1 ? T_NODES - 1 : pos2);
    int v2 = batch[pc];
    bool cb = (lane < 16) && ((pos2 < 0) || (v2 < b));
    bool cf = (lane >= 16) && (lane < 32) && (pos2 < T_NODES) && (v2 == b);
    s_out = wsb + (int)__popcll(__ballot(cb));
    n_out = wsf + (int)__popcll(__ballot(cf)) - s_out;
}

// ---------------------------------------------------------------------------
// Full-wave kNN body (verified R13): fallback path, NS slots/lane, 64 lanes.
// ---------------------------------------------------------------------------
template <int NS>
__device__ __forceinline__ void knn_body(const float* __restrict__ pos,
                                         int t, int s, int n, int lane,
                                         int* __restrict__ nbr,
                                         float4* __restrict__ dird) {
    float px = pos[t * 3 + 0], py = pos[t * 3 + 1], pz = pos[t * 3 + 2];
    float sd[NS];
    int ss[NS];
#pragma unroll
    for (int sl = 0; sl < NS; ++sl) {
        int j = lane + sl * 64;
        float d2 = 1e30f;
        if (j < n) {
            int jj = s + j;
            float dx = px - pos[jj * 3 + 0];
            float dy = py - pos[jj * 3 + 1];
            float dz = pz - pos[jj * 3 + 2];
            d2 = dx * dx + dy * dy + dz * dz;
        }
        sd[sl] = d2;
        ss[sl] = sl;
    }
#pragma unroll
    for (int p = 1; p < NS; p <<= 1) {
#pragma unroll
        for (int k = p; k >= 1; k >>= 1) {
#pragma unroll
            for (int j = (k & (p - 1)); j + k < NS; j += 2 * k) {
#pragma unroll
                for (int i = 0; i < k; ++i) {
                    if (i + j + k < NS && ((i + j) / (2 * p)) == ((i + j + k) / (2 * p))) {
                        int a = i + j, c2 = i + j + k;
                        bool sw = sd[a] > sd[c2];
                        float td = sd[a];
                        int ts = ss[a];
                        sd[a] = sw ? sd[c2] : sd[a];
                        ss[a] = sw ? ss[c2] : ss[a];
                        sd[c2] = sw ? td : sd[c2];
                        ss[c2] = sw ? ts : ss[c2];
                    }
                }
            }
        }
    }

    float resd = 1e30f;
    int resj = -1;
#pragma unroll
    for (int r = 0; r < KNN; ++r) {
        float rd = sd[0];
#pragma unroll
        for (int off = 32; off >= 1; off >>= 1) {
            rd = fminf(rd, __shfl_xor(rd, off));
        }
        unsigned long long mask = __ballot(sd[0] == rd);
        int wl = (int)__builtin_ctzll(mask);
        int ws = __shfl(ss[0], wl);
        if (lane == r) { resd = rd; resj = wl + ws * 64; }
        if (lane == wl) {
#pragma unroll
            for (int i = 0; i < NS - 1; ++i) { sd[i] = sd[i + 1]; ss[i] = ss[i + 1]; }
            sd[NS - 1] = 1e30f;
        }
    }

    if (lane < KNN) {
        bool valid = (resd < 1e29f);
        int jf = valid ? (s + resj) : -1;
        nbr[t * KNN + lane] = jf;
        float dd = sqrtf(resd + 1e-6f);
        float dx = 0.f, dy = 0.f, dz = 0.f;
        if (valid) {
            float inv = 1.f / dd;
            dx = (px - pos[jf * 3 + 0]) * inv;
            dy = (py - pos[jf * 3 + 1]) * inv;
            dz = (pz - pos[jf * 3 + 2]) * inv;
        }
        float4 v;
        v.x = dx; v.y = dy; v.z = dz; v.w = dd;
        dird[t * KNN + lane] = v;
    }
}

// ---------------------------------------------------------------------------
// tau-threshold paired kNN (verified R15/R18): 2 nodes/wave, 18 slots/lane.
// ---------------------------------------------------------------------------
__device__ __forceinline__ bool knn_tau(const float* __restrict__ pos,
                                        int t, int s, int n, int lane,
                                        float* __restrict__ ldsD,
                                        int* __restrict__ ldsI,
                                        int* __restrict__ nbr,
                                        float4* __restrict__ dird) {
    const int NS = 18;
    int l32 = lane & 31;
    float px = pos[t * 3 + 0], py = pos[t * 3 + 1], pz = pos[t * 3 + 2];
    float sd[NS];
#pragma unroll
    for (int sl = 0; sl < NS; ++sl) {
        int j = l32 + sl * 32;
        float d2 = 1e30f;
        if (j < n) {
            int jj = s + j;
            float dx = px - pos[jj * 3 + 0];
            float dy = py - pos[jj * 3 + 1];
            float dz = pz - pos[jj * 3 + 2];
            d2 = dx * dx + dy * dy + dz * dz;
        }
        sd[sl] = d2;
    }
    float v = sd[0];
#pragma unroll
    for (int sl = 1; sl < NS; ++sl) v = fminf(v, sd[sl]);
#pragma unroll
    for (int k = 2; k <= 32; k <<= 1) {
#pragma unroll
        for (int j = k >> 1; j > 0; j >>= 1) {
            float o = __shfl_xor(v, j);
            bool up = ((l32 & k) == 0);
            bool lower = ((l32 & j) == 0);
            v = (lower == up) ? fminf(v, o) : fmaxf(v, o);
        }
    }
    float tau = __shfl(v, (lane & 32) + 15);

    int cnt = 0;
#pragma unroll
    for (int sl = 0; sl < NS; ++sl) cnt += (sd[sl] <= tau) ? 1 : 0;
    int pfx = cnt;
#pragma unroll
    for (int off = 1; off < 32; off <<= 1) {
        int y = __shfl(pfx, lane - off);
        if (l32 >= off) pfx += y;
    }
    int M = __shfl(pfx, (lane & 32) + 31);
    if (__ballot(M > 32)) return false;  // rare; fallback

    int wp = pfx - cnt;
    float* bd = ldsD + (lane >> 5) * 32;
    int* bi = ldsI + (lane >> 5) * 32;
#pragma unroll
    for (int sl = 0; sl < NS; ++sl) {
        if (sd[sl] <= tau) { bd[wp] = sd[sl]; bi[wp] = l32 + sl * 32; ++wp; }
    }
    __asm__ volatile("s_waitcnt lgkmcnt(0)" ::: "memory");

    float kd = (l32 < M) ? bd[l32] : 1e30f;
    int ki = (l32 < M) ? bi[l32] : 0;
#pragma unroll
    for (int k = 2; k <= 32; k <<= 1) {
#pragma unroll
        for (int j = k >> 1; j > 0; j >>= 1) {
            float od = __shfl_xor(kd, j);
            int oi = __shfl_xor(ki, j);
            bool up = ((l32 & k) == 0);
            bool lower = ((l32 & j) == 0);
            bool keepMin = (lower == up);
            bool take = keepMin ? (od < kd) : (od > kd);
            kd = keepMin ? fminf(kd, od) : fmaxf(kd, od);
            ki = take ? oi : ki;
        }
    }

    if (l32 < KNN) {
        bool valid = (kd < 1e29f);
        int jf = valid ? (s + ki) : -1;
        nbr[t * KNN + l32] = jf;
        float dd = sqrtf(kd + 1e-6f);
        float dx = 0.f, dy = 0.f, dz = 0.f;
        if (valid) {
            float inv = 1.f / dd;
            dx = (px - pos[jf * 3 + 0]) * inv;
            dy = (py - pos[jf * 3 + 1]) * inv;
            dz = (pz - pos[jf * 3 + 2]) * inv;
        }
        float4 vv;
        vv.x = dx; vv.y = dy; vv.z = dz; vv.w = dd;
        dird[t * KNN + l32] = vv;
    }
    return true;
}

// ---------------------------------------------------------------------------
// Kernel 1: k_par — ONE dispatch, three concurrent roles (mod-3 partition,
// R15/R18 config). qkvv layout: [q(128) | k(128) | v0/v1 interleaved (256)]
// so k_attn Phase B needs ONE float4 gather per neighbor (was two float2).
// ---------------------------------------------------------------------------
__global__ __launch_bounds__(256) void k_par(const float* __restrict__ pos,
                                             const int* __restrict__ batch,
                                             const float* __restrict__ x,
                                             const float* __restrict__ embW,
                                             const float* __restrict__ embb,
                                             const float* __restrict__ Wq,
                                             const float* __restrict__ Wk,
                                             const float* __restrict__ Wv0,
                                             const float* __restrict__ Wv1,
                                             const float* __restrict__ Wo0,
                                             const float* __restrict__ Wg,
                                             const float* __restrict__ headW,
                                             int* __restrict__ nbr,
                                             float4* __restrict__ dird,
                                             float* __restrict__ qkvv,
                                             float* __restrict__ poolF0,
                                             float* __restrict__ H1,
                                             float* __restrict__ H2) {
    __shared__ float smem[CDIM * 20];  // 10 KB: qkv tile / headW / knn bufD
    __shared__ int smemi[256];         // role A bufI
    int bid = blockIdx.x;
    int tid = threadIdx.x;

    if (bid >= 1536) {
        // ---- role C: H1/H2 = {Wo0,Wg} @ headW ----
        int m = bid - 1536;
        const float* W = m ? Wg : Wo0;
        float* H = m ? H2 : H1;
        for (int i = tid; i < CDIM * 19; i += 256) smem[i] = headW[i];
        __syncthreads();
        for (int i = tid; i < CDIM * 19; i += 256) {
            int c = i / 19, o = i - c * 19;
            float acc = 0.f;
#pragma unroll 8
            for (int d = 0; d < CDIM; ++d) acc += W[c * CDIM + d] * smem[d * 19 + o];
            H[i] = acc;
        }
        return;
    }

    int g = bid / 3, r = bid - g * 3;
    if (r == 2) {
        // ---- role B: embed + QKV for nodes [g*16, g*16+16), f0 pooled ----
        float (*sf)[CDIM] = (float (*)[CDIM])smem;
        int t0 = g * 16;
        {
            int col = tid & 127;
            int pr = tid >> 7;
            float ew[11];
#pragma unroll
            for (int i = 0; i < 11; ++i) ew[i] = embW[i * CDIM + col];
            float eb = embb[col];
            float acc_run = 0.f;
            int gprev = batch[t0 + pr * 8];
#pragma unroll
            for (int nn8 = 0; nn8 < 8; ++nn8) {
                int nn = pr * 8 + nn8;
                int t = t0 + nn;
                float acc = eb;
#pragma unroll
                for (int i = 0; i < 11; ++i) acc += x[t * 11 + i] * ew[i];
                sf[nn][col] = acc;
                int gb = batch[t];
                if (gb != gprev) {
                    atomicAdd(&poolF0[gprev * CDIM + col], acc_run);
                    acc_run = 0.f;
                    gprev = gb;
                }
                acc_run += acc;
            }
            atomicAdd(&poolF0[gprev * CDIM + col], acc_run);
        }
        __syncthreads();

        const float* W1 = (tid < 128) ? Wq : Wk;    // wave-uniform
        const float* W2 = (tid < 128) ? Wv0 : Wv1;  // wave-uniform
        int col = tid & 127;
        // v-interleave: v0_c -> 256+2c, v1_c -> 256+2c+1
        int voff = 256 + 2 * col + (tid >> 7);

        float acc1[16], acc2[16];
#pragma unroll
        for (int nn = 0; nn < 16; ++nn) { acc1[nn] = 0.f; acc2[nn] = 0.f; }

        for (int c0 = 0; c0 < CDIM; c0 += 8) {
            float w1[8], w2[8];
#pragma unroll
            for (int cc = 0; cc < 8; ++cc) {
                w1[cc] = W1[(c0 + cc) * CDIM + col];
                w2[cc] = W2[(c0 + cc) * CDIM + col];
            }
#pragma unroll
            for (int nn = 0; nn < 16; ++nn) {
                float4 fa = *(const float4*)&sf[nn][c0];
                float4 fb = *(const float4*)&sf[nn][c0 + 4];
                acc1[nn] += fa.x * w1[0] + fa.y * w1[1] + fa.z * w1[2] + fa.w * w1[3]
                          + fb.x * w1[4] + fb.y * w1[5] + fb.z * w1[6] + fb.w * w1[7];
                acc2[nn] += fa.x * w2[0] + fa.y * w2[1] + fa.z * w2[2] + fa.w * w2[3]
                          + fb.x * w2[4] + fb.y * w2[5] + fb.z * w2[6] + fb.w * w2[7];
            }
        }
#pragma unroll
        for (int nn = 0; nn < 16; ++nn) {
            qkvv[(size_t)(t0 + nn) * 512 + tid] = acc1[nn];   // q|k
            qkvv[(size_t)(t0 + nn) * 512 + voff] = acc2[nn];  // v-interleaved
        }
        return;
    }

    // ---- role A: kNN, 2 nodes per wave (8 per block) ----
    int kidx = g * 2 + r;           // 0..1023
    int wave = tid >> 6;
    int lane = tid & 63;
    int tA = kidx * 8 + wave * 2;
    int tB = tA + 1;

    int sA, nA, sB, nB;
    seg_probe(batch, tA, lane, sA, nA);
    if (batch[tB] == batch[tA]) {   // wave-uniform; ~511/512 of waves
        sB = sA; nB = nA;
    } else {
        seg_probe(batch, tB, lane, sB, nB);
    }

    float* ldsD = smem + wave * 64;
    int* ldsI = smemi + wave * 64;

    int nmax = nA > nB ? nA : nB;
    bool done = false;
    if (nmax <= 576) {
        int t = (lane < 32) ? tA : tB;
        int s = (lane < 32) ? sA : sB;
        int n = (lane < 32) ? nA : nB;
        done = knn_tau(pos, t, s, n, lane, ldsD, ldsI, nbr, dird);
    }
    if (!done) {
        knn_body<16>(pos, tA, sA, nA, lane, nbr, dird);
        knn_body<16>(pos, tB, sB, nB, lane, nbr, dird);
    }
}

// ---------------------------------------------------------------------------
// Kernel 2: fused kNN attention + equivariant mix + per-graph pooling.
// Phase B now does ONE float4 gather per neighbor ({v0,v1} interleaved).
// ---------------------------------------------------------------------------
__global__ __launch_bounds__(256) void k_attn(const float* __restrict__ qkvv,
                                              const int* __restrict__ nbr,
                                              const float4* __restrict__ dird,
                                              const int* __restrict__ batch,
                                              const float* __restrict__ dist_scale,
                                              const float* __restrict__ Wo1,
                                              float* __restrict__ poolO0,
                                              float* __restrict__ poolInv) {
    __shared__ float  s_a[4][64];          // [node][h*16+k]
    __shared__ float4 s_d[4][16];          // dird per node
    __shared__ int    s_j[4][16];          // neighbor ids
    __shared__ float  s_o1[4][CDIM][4];    // [node][c][x,y,z,out0] = 8 KB
    __shared__ float  s_part[CDIM][13];    // half-1 partials, padded stride
    __shared__ int    s_gid[4];            // graph ids of the 4 nodes

    int bid = blockIdx.x;
    int swz = (bid & 7) * (T_NODES / 32) + (bid >> 3);  // XCD swizzle (bijective)
    int wave = threadIdx.x >> 6;
    int lane = threadIdx.x & 63;
    int t0 = swz * 4;
    int t = t0 + wave;

    if (threadIdx.x < 4) s_gid[threadIdx.x] = batch[t0 + threadIdx.x];

    // ---- Phase A: logits + softmax. lane = (k, h) ----
    int k = lane & 15;
    int h = lane >> 4;

    int j = nbr[t * KNN + k];
    float4 dv = dird[t * KNN + k];
    if (h == 0) { s_j[wave][k] = j; s_d[wave][k] = dv; }

    const float4* qv = (const float4*)&qkvv[(size_t)t * 512 + h * DHEAD];
    const float4* kv = (j >= 0) ? (const float4*)&qkvv[(size_t)j * 512 + 128 + h * DHEAD] : qv;
    float dot = 0.f;
#pragma unroll
    for (int i = 0; i < 8; ++i) {
        float4 a = qv[i], b2 = kv[i];
        dot += a.x * b2.x + a.y * b2.y + a.z * b2.z + a.w * b2.w;
    }
    float xs = dist_scale[h];
    float sp = (xs > 20.f) ? xs : log1pf(expf(xs));  // softplus
    float lg = (j >= 0) ? (dot * 0.17677669529663687f - sp * dv.w) : -1e30f;

    float m = lg;
    m = fmaxf(m, __shfl_xor(m, 1));
    m = fmaxf(m, __shfl_xor(m, 2));
    m = fmaxf(m, __shfl_xor(m, 4));
    m = fmaxf(m, __shfl_xor(m, 8));
    float e = expf(lg - m);
    float ssum = e;
    ssum += __shfl_xor(ssum, 1);
    ssum += __shfl_xor(ssum, 2);
    ssum += __shfl_xor(ssum, 4);
    ssum += __shfl_xor(ssum, 8);
    s_a[wave][h * 16 + k] = e / ssum;

    __syncthreads();

    // ---- Phase B: PV accumulate. lane handles channels 2*lane, 2*lane+1;
    //      ONE float4 gather per neighbor: {v0[c2], v1[c2], v0[c2+1], v1[c2+1]}
    int c2 = lane * 2;
    int hh = lane >> 4;

    float o0x = 0.f, o0y = 0.f;
    float o1xx = 0.f, o1xy = 0.f;
    float o1yx = 0.f, o1yy = 0.f;
    float o1zx = 0.f, o1zy = 0.f;

#pragma unroll
    for (int kk = 0; kk < KNN; ++kk) {
        int jj = s_j[wave][kk];
        if (jj >= 0) {
            float a = s_a[wave][hh * 16 + kk];
            float4 d = s_d[wave][kk];
            float4 vv = *(const float4*)&qkvv[(size_t)jj * 512 + 256 + c2 * 2];
            o0x += a * vv.x;
            o0y += a * vv.z;
            float w1x = a * vv.y, w1y = a * vv.w;
            o1xx += w1x * d.x; o1xy += w1y * d.x;
            o1yx += w1x * d.y; o1yy += w1y * d.y;
            o1zx += w1x * d.z; o1zy += w1y * d.z;
        }
    }

    {
        float4 w0; w0.x = o1xx; w0.y = o1yx; w0.z = o1zx; w0.w = o0x;
        float4 w1; w1.x = o1xy; w1.y = o1yy; w1.z = o1zy; w1.w = o0y;
        *(float4*)&s_o1[wave][c2][0] = w0;
        *(float4*)&s_o1[wave][c2 + 1][0] = w1;
    }
    __syncthreads();

    // ---- Phase C: block-cooperative f1 = out1 @ Wo1, pooled atomics ----
    int d = threadIdx.x & 127;
    int half = threadIdx.x >> 7;

    float acc[4][3];
#pragma unroll
    for (int nn = 0; nn < 4; ++nn) { acc[nn][0] = 0.f; acc[nn][1] = 0.f; acc[nn][2] = 0.f; }

    int cb0 = half * 64;
#pragma unroll 4
    for (int c = cb0; c < cb0 + 64; ++c) {
        float wv = Wo1[c * CDIM + d];  // coalesced row read, L2-hot
#pragma unroll
        for (int nn = 0; nn < 4; ++nn) {
            float4 v = *(const float4*)&s_o1[nn][c][0];  // broadcast
            acc[nn][0] += v.x * wv;
            acc[nn][1] += v.y * wv;
            acc[nn][2] += v.z * wv;
        }
    }
    if (half == 1) {
#pragma unroll
        for (int nn = 0; nn < 4; ++nn) {
            s_part[d][nn * 3 + 0] = acc[nn][0];
            s_part[d][nn * 3 + 1] = acc[nn][1];
            s_part[d][nn * 3 + 2] = acc[nn][2];
        }
    }
    __syncthreads();
    if (half == 0) {
        float accO = 0.f, accI = 0.f;
        int gprev = s_gid[0];
#pragma unroll
        for (int nn = 0; nn < 4; ++nn) {
            float fx = acc[nn][0] + s_part[d][nn * 3 + 0];
            float fy = acc[nn][1] + s_part[d][nn * 3 + 1];
            float fz = acc[nn][2] + s_part[d][nn * 3 + 2];
            float iv = sqrtf(fx * fx + fy * fy + fz * fz + 1e-6f);
            float o0v = s_o1[nn][d][3];
            int gb = s_gid[nn];
            if (gb != gprev) {
                atomicAdd(&poolO0[gprev * CDIM + d], accO);
                atomicAdd(&poolInv[gprev * CDIM + d], accI);
                accO = 0.f; accI = 0.f;
                gprev = gb;
            }
            accO += o0v;
            accI += iv;
        }
        atomicAdd(&poolO0[gprev * CDIM + d], accO);
        atomicAdd(&poolInv[gprev * CDIM + d], accI);
    }
}

// ---------------------------------------------------------------------------
// Kernel 3: tiny head — normalize pooled sums, apply headW/H1/H2 + bias.
// ---------------------------------------------------------------------------
__global__ __launch_bounds__(640) void k_pool(const float* __restrict__ poolF0,
                                              const float* __restrict__ poolO0,
                                              const float* __restrict__ poolInv,
                                              const int* __restrict__ batch,
                                              const float* __restrict__ headW,
                                              const float* __restrict__ H1,
                                              const float* __restrict__ H2,
                                              const float* __restrict__ headb,
                                              float* __restrict__ out) {
    __shared__ float P0[CDIM], P1[CDIM], P2[CDIM];
    int b = blockIdx.x;
    int tid = threadIdx.x;

    int lo = 0, hi = T_NODES;
    while (lo < hi) {
        int mid = (lo + hi) >> 1;
        bool lt = batch[mid] < b;
        lo = lt ? mid + 1 : lo;
        hi = lt ? hi : mid;
    }
    int s = lo;
    lo = 0; hi = T_NODES;
    while (lo < hi) {
        int mid = (lo + hi) >> 1;
        bool le = batch[mid] <= b;
        lo = le ? mid + 1 : lo;
        hi = le ? hi : mid;
    }
    int n = lo - s;
    float inv_n = 1.f / fmaxf((float)n, 1.f);

    if (tid < CDIM) {
        P0[tid] = poolF0[b * CDIM + tid] * inv_n;
        P1[tid] = poolO0[b * CDIM + tid] * inv_n;
        P2[tid] = poolInv[b * CDIM + tid] * inv_n;
    }
    __syncthreads();

    if (tid < 19 * 32) {
        int o = tid >> 5;
        int l = tid & 31;
        float p = 0.f;
#pragma unroll
        for (int cc = 0; cc < 4; ++cc) {
            int ch = l + cc * 32;
            p += P0[ch] * headW[ch * 19 + o]
               + P1[ch] * H1[ch * 19 + o]
               + P2[ch] * H2[ch * 19 + o];
        }
        p += __shfl_xor(p, 16);
        p += __shfl_xor(p, 8);
        p += __shfl_xor(p, 4);
        p += __shfl_xor(p, 2);
        p += __shfl_xor(p, 1);
        if (l == 0) out[b * 19 + o] = p + headb[o];
    }
}

// ---------------------------------------------------------------------------
extern "C" void kernel_launch(void* const* d_in, const int* in_sizes, int n_in,
                              void* d_out, int out_size, void* d_ws, size_t ws_size,
                              hipStream_t stream) {
    const float* x    = (const float*)d_in[0];   // [T,11]
    const float* pos  = (const float*)d_in[1];   // [T,3]
    const int* batch  = (const int*)d_in[2];     // [T]
    const float* embW = (const float*)d_in[3];   // [11,128]
    const float* embb = (const float*)d_in[4];   // [128]
    const float* Wq   = (const float*)d_in[5];
    const float* Wk   = (const float*)d_in[6];
    const float* Wv0  = (const float*)d_in[7];
    const float* Wv1  = (const float*)d_in[8];
    const float* Wo0  = (const float*)d_in[9];
    const float* Wo1  = (const float*)d_in[10];
    const float* Wg   = (const float*)d_in[11];
    const float* dist_scale = (const float*)d_in[12];  // [4]
    const float* headW = (const float*)d_in[13];       // [128,19]
    const float* headb = (const float*)d_in[14];       // [19]
    float* out = (float*)d_out;                        // [16,19]

    char* w = (char*)d_ws;
    float* qkvv = (float*)(w + 256);
    int* nbr    = (int*)(qkvv + (size_t)T_NODES * 512);
    float4* dird = (float4*)(nbr + (size_t)T_NODES * KNN);  // [T][K] {dx,dy,dz,dist}
    float* poolF0 = (float*)(dird + (size_t)T_NODES * KNN); // [16][128] x3 contiguous
    float* poolO0 = poolF0 + BGRAPHS * CDIM;
    float* poolInv = poolO0 + BGRAPHS * CDIM;
    float* H1   = poolInv + BGRAPHS * CDIM;
    float* H2   = H1 + CDIM * 19;

    hipMemsetAsync(poolF0, 0, 3 * BGRAPHS * CDIM * sizeof(float), stream);
    k_par<<<1538, 256, 0, stream>>>(pos, batch, x, embW, embb, Wq, Wk, Wv0, Wv1,
                                    Wo0, Wg, headW, nbr, dird, qkvv, poolF0, H1, H2);
    k_attn<<<T_NODES / 4, 256, 0, stream>>>(qkvv, nbr, dird, batch, dist_scale, Wo1,
                                            poolO0, poolInv);
    k_pool<<<BGRAPHS, 640, 0, stream>>>(poolF0, poolO0, poolInv, batch, headW,
                                        H1, H2, headb, out);
}